// Round 8
// baseline (71.806 us; speedup 1.0000x reference)
//
#include <hip/hip_runtime.h>
#include <hip/hip_bf16.h>
#include <cmath>

#define B_ 4
#define T_ 2048
#define C_ 1024
#define H_ 64
#define SCALE_ 0.03125f          /* 1024^-0.5 */
#define K2_ 0.04508422003f       /* SCALE_ * log2(e) */
#define THRRAW_ 177.0f           /* defer-max threshold: 8 / K2_ */
#define NEG_ -3.0e38f

typedef __attribute__((ext_vector_type(4))) float f32x4;
typedef __attribute__((ext_vector_type(8))) short s16x8;
typedef __attribute__((ext_vector_type(4))) unsigned short u16x4;

__device__ inline unsigned short f2bf(float f) {
    union { __hip_bfloat16 h; unsigned short u; } cv;
    cv.h = __float2bfloat16(f);
    return cv.u;
}

// ---------------- W prep: Wt[c][k] = bf16(W[mat][k][col]), c = mat*64+col ----
__global__ __launch_bounds__(256) void wprep(
    const float* __restrict__ Wq, const float* __restrict__ Wk,
    const float* __restrict__ Wv, unsigned short* __restrict__ wt)
{
    const int g = blockIdx.x * 256 + threadIdx.x;
    const int c = g >> 7;             // 0..191, wave-uniform
    const int kg = (g & 127) * 8;
    const float* W = (c < 64) ? Wq : (c < 128) ? Wk : Wv;
    const int col = c & 63;
    u16x4 a, b;
    a.x = f2bf(W[(size_t)(kg + 0) * H_ + col]);
    a.y = f2bf(W[(size_t)(kg + 1) * H_ + col]);
    a.z = f2bf(W[(size_t)(kg + 2) * H_ + col]);
    a.w = f2bf(W[(size_t)(kg + 3) * H_ + col]);
    b.x = f2bf(W[(size_t)(kg + 4) * H_ + col]);
    b.y = f2bf(W[(size_t)(kg + 5) * H_ + col]);
    b.z = f2bf(W[(size_t)(kg + 6) * H_ + col]);
    b.w = f2bf(W[(size_t)(kg + 7) * H_ + col]);
    *(u16x4*)&wt[(size_t)c * C_ + kg] = a;
    *(u16x4*)&wt[(size_t)c * C_ + kg + 4] = b;
}

// ---------------- streaming projection: NO barriers in K-loop ----------------
// Grid 512 (16-row tiles), 4 waves x 48 cols. A-frags straight from global x
// (L1-shared across waves), B-frags from L2-resident Wt. Deep ILP via unroll.
__global__ __launch_bounds__(256) void proj_stream(
    const float* __restrict__ x, const unsigned short* __restrict__ wt,
    unsigned short* __restrict__ qb, unsigned short* __restrict__ kb,
    unsigned short* __restrict__ vt)
{
    __shared__ alignas(16) unsigned short Sh[64 * 20];   // epilogue V transpose only

    const int t = threadIdx.x, lane = t & 63, w = t >> 6;
    const int fr = lane & 15, hi4 = lane >> 4, ko = hi4 * 8;
    const int row0 = blockIdx.x * 16;
    const int wc = w * 48;

    f32x4 acc[3];
    #pragma unroll
    for (int n = 0; n < 3; ++n) acc[n] = (f32x4){0.f, 0.f, 0.f, 0.f};

    const float* xr = x + (size_t)(row0 + fr) * C_ + ko;
    const unsigned short* w0 = wt + (size_t)(wc + fr) * C_ + ko;
    const unsigned short* w1 = wt + (size_t)(wc + 16 + fr) * C_ + ko;
    const unsigned short* w2 = wt + (size_t)(wc + 32 + fr) * C_ + ko;

    #pragma unroll 4
    for (int kk = 0; kk < C_; kk += 32) {
        f32x4 x0 = *(const f32x4*)(xr + kk);
        f32x4 x1 = *(const f32x4*)(xr + kk + 4);
        s16x8 af;
        af[0] = (short)f2bf(x0.x); af[1] = (short)f2bf(x0.y);
        af[2] = (short)f2bf(x0.z); af[3] = (short)f2bf(x0.w);
        af[4] = (short)f2bf(x1.x); af[5] = (short)f2bf(x1.y);
        af[6] = (short)f2bf(x1.z); af[7] = (short)f2bf(x1.w);
        s16x8 b0 = *(const s16x8*)(w0 + kk);
        s16x8 b1 = *(const s16x8*)(w1 + kk);
        s16x8 b2 = *(const s16x8*)(w2 + kk);
        acc[0] = __builtin_amdgcn_mfma_f32_16x16x32_bf16(af, b0, acc[0], 0, 0, 0);
        acc[1] = __builtin_amdgcn_mfma_f32_16x16x32_bf16(af, b1, acc[1], 0, 0, 0);
        acc[2] = __builtin_amdgcn_mfma_f32_16x16x32_bf16(af, b2, acc[2], 0, 0, 0);
    }

    // ---- epilogue. C/D: col = fr, row = hi4*4 + j ----
    const int bb = row0 >> 11, trow = row0 & 2047;
    #pragma unroll
    for (int n = 0; n < 3; ++n) {
        int c = wc + n * 16 + fr;        // frag-uniform mat (16-aligned ranges)
        if (c < 128) {
            unsigned short* outb = (c < 64) ? qb : kb;
            int cc = c & 63;
            #pragma unroll
            for (int j = 0; j < 4; ++j)
                outb[(size_t)(row0 + hi4 * 4 + j) * H_ + cc] = f2bf(acc[n][j]);
        } else {
            int h = c - 128;
            #pragma unroll
            for (int j = 0; j < 4; ++j)
                Sh[h * 20 + hi4 * 4 + j] = f2bf(acc[n][j]);   // Ltr[h][t]
        }
    }
    __syncthreads();
    {
        int h = t >> 2, tg = (t & 3) * 4;
        u16x4 vv = *(const u16x4*)&Sh[h * 20 + tg];
        *(u16x4*)&vt[(size_t)bb * (H_ * T_) + (size_t)h * T_ + trow + tg] = vv;
    }
}

// ---------------- MFMA flash attention (identical to R5/R7) ----------------
__global__ __launch_bounds__(512, 4) void attn_mfma(
    const unsigned short* __restrict__ qb, const unsigned short* __restrict__ kb,
    const unsigned short* __restrict__ vt, float* __restrict__ out)
{
    __shared__ alignas(16) unsigned short Ps[8][1024];  // per-wave P (swizzled)
    __shared__ float Os[8][16][68];
    __shared__ float Mm[8][16];
    __shared__ float Ll[8][16];

    const int t = threadIdx.x, lane = t & 63, w = t >> 6;
    const int fr = lane & 15, hi4 = lane >> 4;
    const int blk = blockIdx.x;
    const int b = blk & 3;
    const int qt = 127 - (blk >> 2);     // big q-tiles dispatch first
    const int qbase = qt * 16;

    const unsigned short* qp = qb + ((size_t)b * T_ + qbase) * H_;
    const unsigned short* kp = kb + (size_t)b * T_ * H_;
    const unsigned short* vp = vt + (size_t)b * H_ * T_;

    // Q frag: lane supplies Q[q=fr][k=8*hi4..+7] — B-operand of mfma(K,Q)
    s16x8 qf0 = *(const s16x8*)&qp[fr * H_ + hi4 * 8];
    s16x8 qf1 = *(const s16x8*)&qp[fr * H_ + 32 + hi4 * 8];

    const int nt = (qbase + 79) >> 6;    // tiles covering keys 0..qbase+15
    const int per = (nt + 7) >> 3;
    const int tb = w * per;
    int te = tb + per; if (te > nt) te = nt;

    float m = NEG_, l = 0.f;
    f32x4 o[4];
    #pragma unroll
    for (int hf = 0; hf < 4; ++hf) o[hf] = (f32x4){0.f, 0.f, 0.f, 0.f};

    unsigned short* P = &Ps[w][0];
    const int swz = (fr & 3) << 4;
    const int qrow = qbase + fr;

    for (int kt = tb; kt < te; ++kt) {
        const int kt0 = kt << 6;

        // ---- QK^T swapped: D[row=key][col=q]; lane owns q-row fr, 16 keys ----
        f32x4 s[4];
        #pragma unroll
        for (int n = 0; n < 4; ++n) {
            const unsigned short* kr = &kp[(size_t)(kt0 + n * 16 + fr) * H_ + hi4 * 8];
            s16x8 kf0 = *(const s16x8*)kr;
            s16x8 kf1 = *(const s16x8*)(kr + 32);
            f32x4 a = (f32x4){0.f, 0.f, 0.f, 0.f};
            a = __builtin_amdgcn_mfma_f32_16x16x32_bf16(kf0, qf0, a, 0, 0, 0);
            a = __builtin_amdgcn_mfma_f32_16x16x32_bf16(kf1, qf1, a, 0, 0, 0);
            s[n] = a;
        }

        // ---- issue V loads now; consumed after softmax (latency hidden) ----
        s16x8 vf[4][2];
        #pragma unroll
        for (int hf = 0; hf < 4; ++hf) {
            const unsigned short* vr = &vp[(size_t)(hf * 16 + fr) * T_ + kt0 + hi4 * 8];
            vf[hf][0] = *(const s16x8*)vr;
            vf[hf][1] = *(const s16x8*)(vr + 32);
        }

        // ---- causal mask in raw domain (boundary tiles only; kt0 <= qbase) ----
        if (kt0 + 63 > qbase) {
            #pragma unroll
            for (int n = 0; n < 4; ++n)
                #pragma unroll
                for (int j = 0; j < 4; ++j) {
                    int key = kt0 + n * 16 + hi4 * 4 + j;
                    s[n][j] = (key > qrow) ? NEG_ : s[n][j];
                }
        }

        // ---- defer-max online softmax ----
        float mxl = fmaxf(fmaxf(fmaxf(fmaxf(s[0][0], s[0][1]), fmaxf(s[0][2], s[0][3])),
                                fmaxf(fmaxf(s[1][0], s[1][1]), fmaxf(s[1][2], s[1][3]))),
                          fmaxf(fmaxf(fmaxf(s[2][0], s[2][1]), fmaxf(s[2][2], s[2][3])),
                                fmaxf(fmaxf(s[3][0], s[3][1]), fmaxf(s[3][2], s[3][3]))));
        if (!__all(mxl - m <= THRRAW_)) {
            float mx = fmaxf(mxl, __shfl_xor(mxl, 16));
            mx = fmaxf(mx, __shfl_xor(mx, 32));
            float mn = fmaxf(m, mx);
            float corr = exp2f((m - mn) * K2_);
            m = mn;
            l *= corr;
            #pragma unroll
            for (int j = 0; j < 4; ++j) {
                float cj = __shfl(corr, (lane & 48) + hi4 * 4 + j);
                o[0][j] *= cj; o[1][j] *= cj; o[2][j] *= cj; o[3][j] *= cj;
            }
        }
        const float nmk = -m * K2_;
        float sum = 0.f;
        #pragma unroll
        for (int n = 0; n < 4; ++n)
            #pragma unroll
            for (int j = 0; j < 4; ++j) {
                float p = exp2f(fmaf(s[n][j], K2_, nmk));
                s[n][j] = p; sum += p;
            }
        sum += __shfl_xor(sum, 16);
        sum += __shfl_xor(sum, 32);
        l += sum;

        // ---- P -> per-wave LDS: 4x u16x4 writes, XOR-swizzled ----
        #pragma unroll
        for (int n = 0; n < 4; ++n) {
            u16x4 pk;
            pk.x = f2bf(s[n][0]); pk.y = f2bf(s[n][1]);
            pk.z = f2bf(s[n][2]); pk.w = f2bf(s[n][3]);
            *(u16x4*)&P[fr * 64 + ((n * 16 + hi4 * 4) ^ swz)] = pk;
        }
        s16x8 pa0 = *(const s16x8*)&P[fr * 64 + ((hi4 * 8) ^ swz)];
        s16x8 pa1 = *(const s16x8*)&P[fr * 64 + ((32 + hi4 * 8) ^ swz)];

        // ---- PV: A = P, B = Vt (preloaded) ----
        #pragma unroll
        for (int hf = 0; hf < 4; ++hf) {
            o[hf] = __builtin_amdgcn_mfma_f32_16x16x32_bf16(pa0, vf[hf][0], o[hf], 0, 0, 0);
            o[hf] = __builtin_amdgcn_mfma_f32_16x16x32_bf16(pa1, vf[hf][1], o[hf], 0, 0, 0);
        }
    }

    // ---- write per-wave partials, combine ----
    if (hi4 == 0) { Mm[w][fr] = m; Ll[w][fr] = l; }
    #pragma unroll
    for (int hf = 0; hf < 4; ++hf)
        #pragma unroll
        for (int j = 0; j < 4; ++j)
            Os[w][hi4 * 4 + j][hf * 16 + fr] = o[hf][j];
    __syncthreads();

    if (t < 256) {
        int qq = t >> 4, h0 = (t & 15) * 4;
        float M = NEG_;
        #pragma unroll
        for (int s8 = 0; s8 < 8; ++s8) M = fmaxf(M, Mm[s8][qq]);
        float L = 0.f;
        f32x4 r = (f32x4){0.f, 0.f, 0.f, 0.f};
        #pragma unroll
        for (int s8 = 0; s8 < 8; ++s8) {
            float e = exp2f((Mm[s8][qq] - M) * K2_);   // raw-domain partials
            L += Ll[s8][qq] * e;
            f32x4 osv = *(const f32x4*)&Os[s8][qq][h0];
            r.x = fmaf(osv.x, e, r.x);
            r.y = fmaf(osv.y, e, r.y);
            r.z = fmaf(osv.z, e, r.z);
            r.w = fmaf(osv.w, e, r.w);
        }
        float il = 1.0f / L;
        r.x *= il; r.y *= il; r.z *= il; r.w *= il;
        *(f32x4*)&out[((size_t)b * T_ + qbase + qq) * H_ + h0] = r;
    }
}

extern "C" void kernel_launch(void* const* d_in, const int* in_sizes, int n_in,
                              void* d_out, int out_size, void* d_ws, size_t ws_size,
                              hipStream_t stream) {
    const float* x  = (const float*)d_in[0];
    const float* Wq = (const float*)d_in[1];
    const float* Wk = (const float*)d_in[2];
    const float* Wv = (const float*)d_in[3];
    float* outp = (float*)d_out;

    unsigned short* base = (unsigned short*)d_ws;
    unsigned short* qbw = base;                    // [8192][64]
    unsigned short* kbw = base + 524288;           // [8192][64]
    unsigned short* vtw = base + 1048576;          // [4][64][2048]
    unsigned short* wtw = base + 1572864;          // [192][1024]

    wprep<<<96, 256, 0, stream>>>(Wq, Wk, Wv, wtw);
    proj_stream<<<B_ * T_ / 16, 256, 0, stream>>>(x, wtw, qbw, kbw, vtw);
    attn_mfma<<<B_ * (T_ / 16), 512, 0, stream>>>(qbw, kbw, vtw, outp);
}

// Round 10
// 50.199 us; speedup vs baseline: 1.4304x; 1.4304x over previous
//
#include <hip/hip_runtime.h>
#include <hip/hip_bf16.h>
#include <cmath>

#define B_ 4
#define T_ 2048
#define C_ 1024
#define H_ 64
#define K2_ 0.04508422003f       /* (1024^-0.5) * log2(e) */
#define THRRAW_ 177.0f           /* defer-max threshold: 8 / K2_ */
#define NEG_ -3.0e38f

typedef __attribute__((ext_vector_type(4))) float f32x4;
typedef __attribute__((ext_vector_type(8))) short s16x8;
typedef __attribute__((ext_vector_type(4))) unsigned short u16x4;
typedef __attribute__((ext_vector_type(8))) unsigned short u16x8;

__device__ inline unsigned short f2bf(float f) {
    union { __hip_bfloat16 h; unsigned short u; } cv;
    cv.h = __float2bfloat16(f);
    return cv.u;
}

#define LDK 72  /* padded k-stride in bf16 elems */

// ---------------- W prep: Wt[c][k] = bf16(W[mat][k][col]), c = mat*64+col ----
__global__ __launch_bounds__(256) void wprep(
    const float* __restrict__ Wq, const float* __restrict__ Wk,
    const float* __restrict__ Wv, unsigned short* __restrict__ wt)
{
    const int g = blockIdx.x * 256 + threadIdx.x;
    const int c = g >> 7;             // 0..191, wave-uniform
    const int kg = (g & 127) * 8;
    const float* W = (c < 64) ? Wq : (c < 128) ? Wk : Wv;
    const int col = c & 63;
    u16x4 a, b;
    a.x = f2bf(W[(size_t)(kg + 0) * H_ + col]);
    a.y = f2bf(W[(size_t)(kg + 1) * H_ + col]);
    a.z = f2bf(W[(size_t)(kg + 2) * H_ + col]);
    a.w = f2bf(W[(size_t)(kg + 3) * H_ + col]);
    b.x = f2bf(W[(size_t)(kg + 4) * H_ + col]);
    b.y = f2bf(W[(size_t)(kg + 5) * H_ + col]);
    b.z = f2bf(W[(size_t)(kg + 6) * H_ + col]);
    b.w = f2bf(W[(size_t)(kg + 7) * H_ + col]);
    *(u16x4*)&wt[(size_t)c * C_ + kg] = a;
    *(u16x4*)&wt[(size_t)c * C_ + kg + 4] = b;
}

// ---------------- projection: 64x64 tile + LDS double-buffer ----------------
// Prefetch tile it+1 into regs right after the barrier; ds_write after compute.
// launch_bounds(256,4) keeps prefetch registers live (R8: default gave 24 VGPR).
// R10 fix: B prefetch is u16x8 (16 B) — 8 k-elems per thread, full tile staged
// (R9 had u16x4 -> half of Bs uninitialized -> NaN).
__global__ __launch_bounds__(256, 4) void proj_dbuf(
    const float* __restrict__ x, const unsigned short* __restrict__ wt,
    unsigned short* __restrict__ qb, unsigned short* __restrict__ kb,
    unsigned short* __restrict__ vt)
{
    __shared__ alignas(16) unsigned short As[2][64 * LDK];   // [buf][row][k]
    __shared__ alignas(16) unsigned short Bs[2][64 * LDK];   // [buf][col][k]

    const int t = threadIdx.x, lane = t & 63, w = t >> 6;
    const int blk = blockIdx.x;
    const int mat = blk % 3;
    const int row0 = (blk / 3) * 64;
    const int wr = (w >> 1) * 32, wc = (w & 1) * 32;
    const int fr = lane & 15, ko = (lane >> 4) * 8;

    // A staging: thread covers rows ar0+16i (i=0..3), 16B each, coalesced.
    //   bytes: 256 thr x 4 x 16B f32 -> 64x64 f32 tile ✓ (bf16 out: 8B x 4)
    const int ar0 = t >> 4, akc = (t & 15) * 4;
    // B staging: thread covers cols bc0+32i (i=0..1), 16B (8 bf16) each.
    //   bytes: 256 thr x 2 x 16B = 8192B = 64x64 bf16 tile ✓
    const int bc0 = t >> 3, bkc = (t & 7) * 8;

    const float* xp = x + (size_t)(row0 + ar0) * C_ + akc;
    const unsigned short* wp = wt + (size_t)(mat * 64 + bc0) * C_ + bkc;

    f32x4 pa[4];
    u16x8 pb[2];

    // prologue: load + store tile 0
    #pragma unroll
    for (int i = 0; i < 4; ++i) pa[i] = *(const f32x4*)(xp + (size_t)i * 16 * C_);
    #pragma unroll
    for (int i = 0; i < 2; ++i) pb[i] = *(const u16x8*)(wp + (size_t)i * 32 * C_);
    #pragma unroll
    for (int i = 0; i < 4; ++i) {
        u16x4 bv;
        bv.x = f2bf(pa[i].x); bv.y = f2bf(pa[i].y);
        bv.z = f2bf(pa[i].z); bv.w = f2bf(pa[i].w);
        *(u16x4*)&As[0][(ar0 + i * 16) * LDK + akc] = bv;
    }
    #pragma unroll
    for (int i = 0; i < 2; ++i)
        *(u16x8*)&Bs[0][(bc0 + i * 32) * LDK + bkc] = pb[i];

    f32x4 acc[2][2];
    #pragma unroll
    for (int mi = 0; mi < 2; ++mi)
        #pragma unroll
        for (int ni = 0; ni < 2; ++ni)
            acc[mi][ni] = (f32x4){0.f, 0.f, 0.f, 0.f};

    for (int it = 0; it < 16; ++it) {
        __syncthreads();
        const int cur = it & 1;
        if (it < 15) {   // issue next tile's loads NOW; consumed after compute
            const float* xn = xp + (it + 1) * 64;
            const unsigned short* wn = wp + (it + 1) * 64;
            #pragma unroll
            for (int i = 0; i < 4; ++i) pa[i] = *(const f32x4*)(xn + (size_t)i * 16 * C_);
            #pragma unroll
            for (int i = 0; i < 2; ++i) pb[i] = *(const u16x8*)(wn + (size_t)i * 32 * C_);
        }
        const unsigned short* A = &As[cur][0];
        const unsigned short* Bb = &Bs[cur][0];
        #pragma unroll
        for (int ks = 0; ks < 2; ++ks) {
            s16x8 a0 = *(const s16x8*)&A[(wr + fr) * LDK + ks * 32 + ko];
            s16x8 a1 = *(const s16x8*)&A[(wr + 16 + fr) * LDK + ks * 32 + ko];
            s16x8 b0 = *(const s16x8*)&Bb[(wc + fr) * LDK + ks * 32 + ko];
            s16x8 b1 = *(const s16x8*)&Bb[(wc + 16 + fr) * LDK + ks * 32 + ko];
            acc[0][0] = __builtin_amdgcn_mfma_f32_16x16x32_bf16(a0, b0, acc[0][0], 0, 0, 0);
            acc[0][1] = __builtin_amdgcn_mfma_f32_16x16x32_bf16(a0, b1, acc[0][1], 0, 0, 0);
            acc[1][0] = __builtin_amdgcn_mfma_f32_16x16x32_bf16(a1, b0, acc[1][0], 0, 0, 0);
            acc[1][1] = __builtin_amdgcn_mfma_f32_16x16x32_bf16(a1, b1, acc[1][1], 0, 0, 0);
        }
        if (it < 15) {   // write tile it+1 into the other buffer
            const int nxt = cur ^ 1;   // last read at it-1; bar(it) separates
            #pragma unroll
            for (int i = 0; i < 4; ++i) {
                u16x4 bv;
                bv.x = f2bf(pa[i].x); bv.y = f2bf(pa[i].y);
                bv.z = f2bf(pa[i].z); bv.w = f2bf(pa[i].w);
                *(u16x4*)&As[nxt][(ar0 + i * 16) * LDK + akc] = bv;
            }
            #pragma unroll
            for (int i = 0; i < 2; ++i)
                *(u16x8*)&Bs[nxt][(bc0 + i * 32) * LDK + bkc] = pb[i];
        }
    }

    // ---- epilogue (R2-verified). C/D: col = lane&15, row = (lane>>4)*4+reg ----
    if (mat < 2) {
        unsigned short* outb = (mat == 0) ? qb : kb;
        #pragma unroll
        for (int mi = 0; mi < 2; ++mi)
            #pragma unroll
            for (int ni = 0; ni < 2; ++ni)
                #pragma unroll
                for (int j = 0; j < 4; ++j) {
                    int row = row0 + wr + mi * 16 + (lane >> 4) * 4 + j;
                    int col = wc + ni * 16 + fr;
                    outb[(size_t)row * H_ + col] = f2bf(acc[mi][ni][j]);
                }
    } else {
        // transpose V tile through LDS -> vt[b][h][t] coalesced
        __syncthreads();
        unsigned short* Tr = &As[0][0];
        #pragma unroll
        for (int mi = 0; mi < 2; ++mi)
            #pragma unroll
            for (int ni = 0; ni < 2; ++ni)
                #pragma unroll
                for (int j = 0; j < 4; ++j) {
                    int r = wr + mi * 16 + (lane >> 4) * 4 + j;   // local key row
                    int cc = wc + ni * 16 + fr;                   // h
                    Tr[cc * LDK + r] = f2bf(acc[mi][ni][j]);
                }
        __syncthreads();
        int h = t >> 2, c0 = (t & 3) * 16;
        int bb = row0 >> 11, trow = row0 & 2047;
        s16x8 v0 = *(const s16x8*)&Tr[h * LDK + c0];
        s16x8 v1 = *(const s16x8*)&Tr[h * LDK + c0 + 8];
        size_t dst = (size_t)bb * H_ * T_ + (size_t)h * T_ + trow + c0;
        *(s16x8*)&vt[dst] = v0;
        *(s16x8*)&vt[dst + 8] = v1;
    }
}

// ---------------- MFMA flash attention (identical to R5/R7/R8) ----------------
__global__ __launch_bounds__(512, 4) void attn_mfma(
    const unsigned short* __restrict__ qb, const unsigned short* __restrict__ kb,
    const unsigned short* __restrict__ vt, float* __restrict__ out)
{
    __shared__ alignas(16) unsigned short Ps[8][1024];  // per-wave P (swizzled)
    __shared__ float Os[8][16][68];
    __shared__ float Mm[8][16];
    __shared__ float Ll[8][16];

    const int t = threadIdx.x, lane = t & 63, w = t >> 6;
    const int fr = lane & 15, hi4 = lane >> 4;
    const int blk = blockIdx.x;
    const int b = blk & 3;
    const int qt = 127 - (blk >> 2);     // big q-tiles dispatch first
    const int qbase = qt * 16;

    const unsigned short* qp = qb + ((size_t)b * T_ + qbase) * H_;
    const unsigned short* kp = kb + (size_t)b * T_ * H_;
    const unsigned short* vp = vt + (size_t)b * H_ * T_;

    // Q frag: lane supplies Q[q=fr][k=8*hi4..+7] — B-operand of mfma(K,Q)
    s16x8 qf0 = *(const s16x8*)&qp[fr * H_ + hi4 * 8];
    s16x8 qf1 = *(const s16x8*)&qp[fr * H_ + 32 + hi4 * 8];

    const int nt = (qbase + 79) >> 6;    // tiles covering keys 0..qbase+15
    const int per = (nt + 7) >> 3;
    const int tb = w * per;
    int te = tb + per; if (te > nt) te = nt;

    float m = NEG_, l = 0.f;
    f32x4 o[4];
    #pragma unroll
    for (int hf = 0; hf < 4; ++hf) o[hf] = (f32x4){0.f, 0.f, 0.f, 0.f};

    unsigned short* P = &Ps[w][0];
    const int swz = (fr & 3) << 4;
    const int qrow = qbase + fr;

    for (int kt = tb; kt < te; ++kt) {
        const int kt0 = kt << 6;

        // ---- QK^T swapped: D[row=key][col=q]; lane owns q-row fr, 16 keys ----
        f32x4 s[4];
        #pragma unroll
        for (int n = 0; n < 4; ++n) {
            const unsigned short* kr = &kp[(size_t)(kt0 + n * 16 + fr) * H_ + hi4 * 8];
            s16x8 kf0 = *(const s16x8*)kr;
            s16x8 kf1 = *(const s16x8*)(kr + 32);
            f32x4 a = (f32x4){0.f, 0.f, 0.f, 0.f};
            a = __builtin_amdgcn_mfma_f32_16x16x32_bf16(kf0, qf0, a, 0, 0, 0);
            a = __builtin_amdgcn_mfma_f32_16x16x32_bf16(kf1, qf1, a, 0, 0, 0);
            s[n] = a;
        }

        // ---- issue V loads now; consumed after softmax (latency hidden) ----
        s16x8 vf[4][2];
        #pragma unroll
        for (int hf = 0; hf < 4; ++hf) {
            const unsigned short* vr = &vp[(size_t)(hf * 16 + fr) * T_ + kt0 + hi4 * 8];
            vf[hf][0] = *(const s16x8*)vr;
            vf[hf][1] = *(const s16x8*)(vr + 32);
        }

        // ---- causal mask in raw domain (boundary tiles only; kt0 <= qbase) ----
        if (kt0 + 63 > qbase) {
            #pragma unroll
            for (int n = 0; n < 4; ++n)
                #pragma unroll
                for (int j = 0; j < 4; ++j) {
                    int key = kt0 + n * 16 + hi4 * 4 + j;
                    s[n][j] = (key > qrow) ? NEG_ : s[n][j];
                }
        }

        // ---- defer-max online softmax ----
        float mxl = fmaxf(fmaxf(fmaxf(fmaxf(s[0][0], s[0][1]), fmaxf(s[0][2], s[0][3])),
                                fmaxf(fmaxf(s[1][0], s[1][1]), fmaxf(s[1][2], s[1][3]))),
                          fmaxf(fmaxf(fmaxf(s[2][0], s[2][1]), fmaxf(s[2][2], s[2][3])),
                                fmaxf(fmaxf(s[3][0], s[3][1]), fmaxf(s[3][2], s[3][3]))));
        if (!__all(mxl - m <= THRRAW_)) {
            float mx = fmaxf(mxl, __shfl_xor(mxl, 16));
            mx = fmaxf(mx, __shfl_xor(mx, 32));
            float mn = fmaxf(m, mx);
            float corr = exp2f((m - mn) * K2_);
            m = mn;
            l *= corr;
            #pragma unroll
            for (int j = 0; j < 4; ++j) {
                float cj = __shfl(corr, (lane & 48) + hi4 * 4 + j);
                o[0][j] *= cj; o[1][j] *= cj; o[2][j] *= cj; o[3][j] *= cj;
            }
        }
        const float nmk = -m * K2_;
        float sum = 0.f;
        #pragma unroll
        for (int n = 0; n < 4; ++n)
            #pragma unroll
            for (int j = 0; j < 4; ++j) {
                float p = exp2f(fmaf(s[n][j], K2_, nmk));
                s[n][j] = p; sum += p;
            }
        sum += __shfl_xor(sum, 16);
        sum += __shfl_xor(sum, 32);
        l += sum;

        // ---- P -> per-wave LDS: 4x u16x4 writes, XOR-swizzled ----
        #pragma unroll
        for (int n = 0; n < 4; ++n) {
            u16x4 pk;
            pk.x = f2bf(s[n][0]); pk.y = f2bf(s[n][1]);
            pk.z = f2bf(s[n][2]); pk.w = f2bf(s[n][3]);
            *(u16x4*)&P[fr * 64 + ((n * 16 + hi4 * 4) ^ swz)] = pk;
        }
        s16x8 pa0 = *(const s16x8*)&P[fr * 64 + ((hi4 * 8) ^ swz)];
        s16x8 pa1 = *(const s16x8*)&P[fr * 64 + ((32 + hi4 * 8) ^ swz)];

        // ---- PV: A = P, B = Vt (preloaded) ----
        #pragma unroll
        for (int hf = 0; hf < 4; ++hf) {
            o[hf] = __builtin_amdgcn_mfma_f32_16x16x32_bf16(pa0, vf[hf][0], o[hf], 0, 0, 0);
            o[hf] = __builtin_amdgcn_mfma_f32_16x16x32_bf16(pa1, vf[hf][1], o[hf], 0, 0, 0);
        }
    }

    // ---- write per-wave partials, combine ----
    if (hi4 == 0) { Mm[w][fr] = m; Ll[w][fr] = l; }
    #pragma unroll
    for (int hf = 0; hf < 4; ++hf)
        #pragma unroll
        for (int j = 0; j < 4; ++j)
            Os[w][hi4 * 4 + j][hf * 16 + fr] = o[hf][j];
    __syncthreads();

    if (t < 256) {
        int qq = t >> 4, h0 = (t & 15) * 4;
        float M = NEG_;
        #pragma unroll
        for (int s8 = 0; s8 < 8; ++s8) M = fmaxf(M, Mm[s8][qq]);
        float L = 0.f;
        f32x4 r = (f32x4){0.f, 0.f, 0.f, 0.f};
        #pragma unroll
        for (int s8 = 0; s8 < 8; ++s8) {
            float e = exp2f((Mm[s8][qq] - M) * K2_);   // raw-domain partials
            L += Ll[s8][qq] * e;
            f32x4 osv = *(const f32x4*)&Os[s8][qq][h0];
            r.x = fmaf(osv.x, e, r.x);
            r.y = fmaf(osv.y, e, r.y);
            r.z = fmaf(osv.z, e, r.z);
            r.w = fmaf(osv.w, e, r.w);
        }
        float il = 1.0f / L;
        r.x *= il; r.y *= il; r.z *= il; r.w *= il;
        *(f32x4*)&out[((size_t)b * T_ + qbase + qq) * H_ + h0] = r;
    }
}

extern "C" void kernel_launch(void* const* d_in, const int* in_sizes, int n_in,
                              void* d_out, int out_size, void* d_ws, size_t ws_size,
                              hipStream_t stream) {
    const float* x  = (const float*)d_in[0];
    const float* Wq = (const float*)d_in[1];
    const float* Wk = (const float*)d_in[2];
    const float* Wv = (const float*)d_in[3];
    float* outp = (float*)d_out;

    unsigned short* base = (unsigned short*)d_ws;
    unsigned short* qbw = base;                    // [8192][64]
    unsigned short* kbw = base + 524288;           // [8192][64]
    unsigned short* vtw = base + 1048576;          // [4][64][2048]
    unsigned short* wtw = base + 1572864;          // [192][1024]

    wprep<<<96, 256, 0, stream>>>(Wq, Wk, Wv, wtw);
    proj_dbuf<<<(B_ * T_ / 64) * 3, 256, 0, stream>>>(x, wtw, qbw, kbw, vtw);
    attn_mfma<<<B_ * (T_ / 16), 512, 0, stream>>>(qbw, kbw, vtw, outp);
}